// Round 9
// baseline (378.238 us; speedup 1.0000x reference)
//
#include <hip/hip_runtime.h>
#include <hip/hip_bf16.h>
#include <stdint.h>

typedef unsigned short u16;
typedef u16 u16x4 __attribute__((ext_vector_type(4)));
typedef short bf16x8 __attribute__((ext_vector_type(8)));
typedef float f32x4 __attribute__((ext_vector_type(4)));

__device__ __forceinline__ u16 f2bf(float f) {
  union { float f; uint32_t u; } v; v.f = f;
  uint32_t u = v.u;
  return (u16)((u + 0x7fffu + ((u >> 16) & 1u)) >> 16);
}

// ---------------- fused aux: x fp32->bf16  +  W_eff = W + 2*(B@A) -> bf16 ----------------
__global__ __launch_bounds__(256) void aux_kernel(
    const float4* __restrict__ x, u16x4* __restrict__ xb, int n4, int nCvt,
    const float* __restrict__ W, const float* __restrict__ A,
    const float* __restrict__ Bl, u16* __restrict__ Wout, int DIN) {
  if ((int)blockIdx.x < nCvt) {
    int i = blockIdx.x * 256 + threadIdx.x;
    const int stride = nCvt * 256;
    for (; i < n4; i += stride) {
      float4 v = x[i];
      u16x4 o;
      o.x = f2bf(v.x); o.y = f2bf(v.y); o.z = f2bf(v.z); o.w = f2bf(v.w);
      xb[i] = o;
    }
  } else {
    const int n = blockIdx.x - nCvt;
    float bv[16];
#pragma unroll
    for (int r = 0; r < 16; ++r) bv[r] = 2.0f * Bl[n * 16 + r];
    const int iters = DIN / (256 * 4);
    for (int c = 0; c < iters; ++c) {
      const int k = (c * 256 + (int)threadIdx.x) * 4;
      float4 wv = *(const float4*)&W[(size_t)n * DIN + k];
#pragma unroll
      for (int r = 0; r < 16; ++r) {
        const float4 av = *(const float4*)&A[(size_t)r * DIN + k];
        wv.x += bv[r] * av.x;
        wv.y += bv[r] * av.y;
        wv.z += bv[r] * av.z;
        wv.w += bv[r] * av.w;
      }
      u16x4 o;
      o.x = f2bf(wv.x); o.y = f2bf(wv.y); o.z = f2bf(wv.z); o.w = f2bf(wv.w);
      *(u16x4*)&Wout[(size_t)n * DIN + k] = o;
    }
  }
}

// ---------------- 256x256 bf16 GEMM: r5 schedule + frag-contiguous LDS ----------------
// C[M][N] = X[M][K] @ Weff[N][K]^T + bias. 8 waves (2M x 4N), wave out 128x64.
// K-chunk 64 = 2 ks-planes of 32. LDS frag-packed (r8-verified layout):
//   plane(op,par,ks) = 16 frags x 512 u16; frag fid = rows fid*16..+15 x 32 k,
//   lane l at byte l*16 holds row fid*16+(l&15), k-group (l>>4)*8.  A planes at
//   (par*2+ks)*8192, B at +32768. ds_read = shared vaddr + imm offset, 1KB bursts.
// Schedule/gates = r5 verbatim (best measured): 4 phases/chunk, reg double-buffer
// (aE/aO/b0/b1), ONLY 2 gates (VM4+BAR) per chunk inside ph1/ph3. 8 DMA ops/chunk
// in r5's FIFO order -> identical race-free ledger.
#define BM 256
#define BN 256

__global__ __launch_bounds__(512, 2) void gemm_kernel(
    const u16* __restrict__ A, const u16* __restrict__ B,
    const float* __restrict__ bias, float* __restrict__ C,
    int M, int N, int K) {
  extern __shared__ u16 lds[];   // 131072 bytes

  const int tid  = threadIdx.x;
  const int lane = tid & 63;
  const int wid  = tid >> 6;

  // XCD-aware block swizzle (nwg % 8 == 0 by launch)
  const int nwg = gridDim.x;
  const int cpx = nwg >> 3;
  const int f   = ((int)blockIdx.x & 7) * cpx + ((int)blockIdx.x >> 3);
  const int nbx = N / BN;
  const int bx = f % nbx, by = f / nbx;
  const int bm = by * BM, bn = bx * BN;

  const int wmL = (wid >> 2) * 128;
  const int wnL = (wid & 3) * 64;
  const int lr  = lane & 15;
  const int lk  = lane >> 4;

  // frag-read base vaddrs (wave frag base folded in; plane/frag via imm offsets)
  u16* const avp = &lds[lane * 8 + ((wid >> 2) * 8) * 512];
  u16* const bvp = &lds[32768 + lane * 8 + ((wid & 3) * 4) * 512];

  auto ldA = [&](int par, int ks, int mf) -> bf16x8 {
    return *(const bf16x8*)(avp + (par * 2 + ks) * 8192 + mf * 512);
  };
  auto ldB = [&](int par, int ks, int nf) -> bf16x8 {
    return *(const bf16x8*)(bvp + (par * 2 + ks) * 8192 + nf * 512);
  };

  // staging (r8-verified mapping): op i of STG covers frags i*8..i*8+7 of a plane;
  // thread (wid,l) writes frag i*8+wid lane-slot l <- row i*128+wid*16+(l&15),
  // k = kt*64 + ks*32 + (l>>4)*8. Linear dest, per-lane source (rule #21).
  const u16* gA0 = A + (size_t)(bm + wid * 16 + lr) * K + (lk << 3);
  const u16* gB0 = B + (size_t)(bn + wid * 16 + lr) * K + (lk << 3);

  auto stageA = [&](int par, int ks, int kt) {
#pragma unroll
    for (int i = 0; i < 2; ++i)
      __builtin_amdgcn_global_load_lds(
          (__attribute__((address_space(1))) const void*)(gA0 + (size_t)i * 128 * K + kt * 64 + ks * 32),
          (__attribute__((address_space(3))) void*)(&lds[(par * 2 + ks) * 8192 + (i * 8 + wid) * 512]),
          16, 0, 0);
  };
  auto stageB = [&](int par, int ks, int kt) {
#pragma unroll
    for (int i = 0; i < 2; ++i)
      __builtin_amdgcn_global_load_lds(
          (__attribute__((address_space(1))) const void*)(gB0 + (size_t)i * 128 * K + kt * 64 + ks * 32),
          (__attribute__((address_space(3))) void*)(&lds[32768 + (par * 2 + ks) * 8192 + (i * 8 + wid) * 512]),
          16, 0, 0);
  };

  f32x4 acc[8][4];
#pragma unroll
  for (int i = 0; i < 8; ++i)
#pragma unroll
    for (int n = 0; n < 4; ++n) acc[i][n] = f32x4{0.f, 0.f, 0.f, 0.f};

  const int NT = K >> 6;
  // prologue: stage chunk 0 (A00,B00,A01,B01 = 8 DMA ops)
  stageA(0, 0, 0); stageB(0, 0, 0); stageA(0, 1, 0); stageB(0, 1, 0);
  asm volatile("s_waitcnt vmcnt(4)" ::: "memory");   // A00,B00 resident
  __builtin_amdgcn_s_barrier();

  bf16x8 aE[4], aO[4], b0[4], b1[4];
#pragma unroll
  for (int n = 0; n < 4; ++n) b0[n] = ldB(0, 0, n);
#pragma unroll
  for (int m = 0; m < 4; ++m) aE[m] = ldA(0, 0, m);

#define VM4() asm volatile("s_waitcnt vmcnt(4)" ::: "memory")
#define BAR() __builtin_amdgcn_s_barrier()

  for (int t = 0; t < NT; ++t) {
    const int par = t & 1, npar = par ^ 1;
    const int tn = (t + 1 < NT) ? t + 1 : 0;   // wrap keeps vmcnt count uniform

    // ---- phase 0: consume (aE, b0) = ks0 x m0-3 ; prefetch aO = ks0 m4-7 ----
    stageA(npar, 0, tn);
#pragma unroll
    for (int m = 0; m < 4; ++m) aO[m] = ldA(par, 0, 4 + m);
    __builtin_amdgcn_s_setprio(1);
#pragma unroll
    for (int m = 0; m < 4; ++m)
#pragma unroll
      for (int n = 0; n < 4; ++n)
        acc[m][n] = __builtin_amdgcn_mfma_f32_16x16x32_bf16(aE[m], b0[n], acc[m][n], 0, 0, 0);
    __builtin_amdgcn_s_setprio(0);

    // ---- phase 1: consume (aO, b0) = ks0 x m4-7 ; gate ; prefetch (b1, aE) = ks1 ----
    stageB(npar, 0, tn);
    VM4();   // retires A(par,1), B(par,1) -> ks1 planes resident
    BAR();
#pragma unroll
    for (int n = 0; n < 4; ++n) b1[n] = ldB(par, 1, n);
#pragma unroll
    for (int m = 0; m < 4; ++m) aE[m] = ldA(par, 1, m);
    __builtin_amdgcn_s_setprio(1);
#pragma unroll
    for (int m = 0; m < 4; ++m)
#pragma unroll
      for (int n = 0; n < 4; ++n)
        acc[4 + m][n] = __builtin_amdgcn_mfma_f32_16x16x32_bf16(aO[m], b0[n], acc[4 + m][n], 0, 0, 0);
    __builtin_amdgcn_s_setprio(0);

    // ---- phase 2: consume (aE, b1) = ks1 x m0-3 ; prefetch aO = ks1 m4-7 ----
    stageA(npar, 1, tn);
#pragma unroll
    for (int m = 0; m < 4; ++m) aO[m] = ldA(par, 1, 4 + m);
    __builtin_amdgcn_s_setprio(1);
#pragma unroll
    for (int m = 0; m < 4; ++m)
#pragma unroll
      for (int n = 0; n < 4; ++n)
        acc[m][n] = __builtin_amdgcn_mfma_f32_16x16x32_bf16(aE[m], b1[n], acc[m][n], 0, 0, 0);
    __builtin_amdgcn_s_setprio(0);

    // ---- phase 3: consume (aO, b1) = ks1 x m4-7 ; gate ; prefetch (b0, aE) = next ks0 ----
    stageB(npar, 1, tn);
    VM4();   // retires A(npar,0), B(npar,0) -> next chunk's ks0 planes resident
    BAR();
#pragma unroll
    for (int n = 0; n < 4; ++n) b0[n] = ldB(npar, 0, n);
#pragma unroll
    for (int m = 0; m < 4; ++m) aE[m] = ldA(npar, 0, m);
    __builtin_amdgcn_s_setprio(1);
#pragma unroll
    for (int m = 0; m < 4; ++m)
#pragma unroll
      for (int n = 0; n < 4; ++n)
        acc[4 + m][n] = __builtin_amdgcn_mfma_f32_16x16x32_bf16(aO[m], b1[n], acc[4 + m][n], 0, 0, 0);
    __builtin_amdgcn_s_setprio(0);
  }

  // drain wrapped staging DMAs before LDS dealloc / kernel end
  asm volatile("s_waitcnt vmcnt(0)" ::: "memory");
  __builtin_amdgcn_s_barrier();

  // epilogue: C/D layout col = lane&15, row = (lane>>4)*4 + j
#pragma unroll
  for (int nf = 0; nf < 4; ++nf) {
    const int col = bn + wnL + nf * 16 + lr;
    const float bv = bias[col];
#pragma unroll
    for (int mf = 0; mf < 8; ++mf) {
      const int row = bm + wmL + mf * 16 + lk * 4;
#pragma unroll
      for (int j = 0; j < 4; ++j)
        C[(size_t)(row + j) * N + col] = acc[mf][nf][j] + bv;
    }
  }
#undef VM4
#undef BAR
}

extern "C" void kernel_launch(void* const* d_in, const int* in_sizes, int n_in,
                              void* d_out, int out_size, void* d_ws, size_t ws_size,
                              hipStream_t stream) {
  const float* x  = (const float*)d_in[0];
  const float* w  = (const float*)d_in[1];
  const float* lA = (const float*)d_in[2];
  const float* lB = (const float*)d_in[3];
  const float* bs = (const float*)d_in[4];
  float* out = (float*)d_out;

  const int DOUT = in_sizes[4];              // 4096
  const int DIN  = in_sizes[1] / DOUT;       // 4096
  const int M    = in_sizes[0] / DIN;        // 8192

  u16* Xb = (u16*)d_ws;                      // M*DIN bf16
  u16* Wb = Xb + (size_t)M * DIN;            // DOUT*DIN bf16

  const int n4 = (M * DIN) / 4;
  const int nCvt = 2048;
  aux_kernel<<<nCvt + DOUT, 256, 0, stream>>>((const float4*)x, (u16x4*)Xb, n4, nCvt,
                                              w, lA, lB, Wb, DIN);

  (void)hipFuncSetAttribute((const void*)gemm_kernel,
                            hipFuncAttributeMaxDynamicSharedMemorySize, 131072);

  const int nwg = (M / BM) * (DOUT / BN);    // 512
  gemm_kernel<<<nwg, 512, 131072, stream>>>(Xb, Wb, bs, out, M, DOUT, DIN);
}

// Round 10
// 312.898 us; speedup vs baseline: 1.2088x; 1.2088x over previous
//
#include <hip/hip_runtime.h>
#include <hip/hip_bf16.h>
#include <stdint.h>

typedef unsigned short u16;
typedef u16 u16x4 __attribute__((ext_vector_type(4)));
typedef short bf16x8 __attribute__((ext_vector_type(8)));
typedef float f32x4 __attribute__((ext_vector_type(4)));

__device__ __forceinline__ u16 f2bf(float f) {
  union { float f; uint32_t u; } v; v.f = f;
  uint32_t u = v.u;
  return (u16)((u + 0x7fffu + ((u >> 16) & 1u)) >> 16);
}

// ---------------- fused aux ----------------
// blocks [0, nW):        W_eff = W + 2*(B@A) -> bf16, 4 rows/block, r-outer loop
//                        (A loaded once per k-chunk per block: A L2 traffic /4;
//                         heavy blocks FIRST so they start before the cvt backfill)
// blocks [nW, nW+nCvt):  x fp32 -> bf16, grid-stride
__global__ __launch_bounds__(256) void aux_kernel(
    const float4* __restrict__ x, u16x4* __restrict__ xb, int n4, int nW, int nCvt,
    const float* __restrict__ W, const float* __restrict__ A,
    const float* __restrict__ Bl, u16* __restrict__ Wout, int DIN) {
  if ((int)blockIdx.x < nW) {
    const int n0 = (int)blockIdx.x * 4;
    float bv[4][16];   // uniform -> scalar regs
#pragma unroll
    for (int j = 0; j < 4; ++j)
#pragma unroll
      for (int r = 0; r < 16; ++r) bv[j][r] = 2.0f * Bl[(n0 + j) * 16 + r];
    const int iters = DIN / (256 * 4);
    for (int c = 0; c < iters; ++c) {
      const int k = (c * 256 + (int)threadIdx.x) * 4;
      float4 wv[4];
#pragma unroll
      for (int j = 0; j < 4; ++j)
        wv[j] = *(const float4*)&W[(size_t)(n0 + j) * DIN + k];
#pragma unroll
      for (int r = 0; r < 16; ++r) {
        const float4 av = *(const float4*)&A[(size_t)r * DIN + k];
#pragma unroll
        for (int j = 0; j < 4; ++j) {
          wv[j].x += bv[j][r] * av.x;
          wv[j].y += bv[j][r] * av.y;
          wv[j].z += bv[j][r] * av.z;
          wv[j].w += bv[j][r] * av.w;
        }
      }
#pragma unroll
      for (int j = 0; j < 4; ++j) {
        u16x4 o;
        o.x = f2bf(wv[j].x); o.y = f2bf(wv[j].y);
        o.z = f2bf(wv[j].z); o.w = f2bf(wv[j].w);
        *(u16x4*)&Wout[(size_t)(n0 + j) * DIN + k] = o;
      }
    }
  } else {
    int i = ((int)blockIdx.x - nW) * 256 + threadIdx.x;
    const int stride = nCvt * 256;
    for (; i < n4; i += stride) {
      float4 v = x[i];
      u16x4 o;
      o.x = f2bf(v.x); o.y = f2bf(v.y); o.z = f2bf(v.z); o.w = f2bf(v.w);
      xb[i] = o;
    }
  }
}

// ---------------- 256x256 deep-pipelined bf16 GEMM (r5 champion, UNCHANGED) ----------------
// C[M][N] = X[M][K] @ Weff[N][K]^T + bias
// Round-2 schedule + ledger (race-free, 0 bank conflicts) + software-pipelined
// register double-buffer: each phase prefetches the NEXT phase's fragments;
// MFMAs consume regs read one phase earlier. 2 gates (vmcnt(4)+BAR) per 64-k chunk.
#define BM 256
#define BN 256

__global__ __launch_bounds__(512, 2) void gemm256_kernel(
    const u16* __restrict__ A, const u16* __restrict__ B,
    const float* __restrict__ bias, float* __restrict__ C,
    int M, int N, int K) {
  extern __shared__ u16 lds[];   // 131072 bytes

  const int tid  = threadIdx.x;
  const int lane = tid & 63;
  const int wid  = tid >> 6;

  // XCD-aware block swizzle (nwg % 8 == 0 by launch)
  const int nwg = gridDim.x;
  const int cpx = nwg >> 3;
  const int f   = ((int)blockIdx.x & 7) * cpx + ((int)blockIdx.x >> 3);
  const int nbx = N / BN;
  const int bx = f % nbx, by = f / nbx;
  const int bm = by * BM, bn = bx * BN;

  const int wmL = (wid >> 2) * 128;
  const int wnL = (wid & 3) * 64;
  const int lr  = lane & 15;
  const int lk  = lane >> 4;
  const int rslot = ((lk ^ ((lr >> 1) & 3)) << 3);  // swizzled k-slot (u16 offset)

  // staging: linear LDS dest, pre-swizzled global source (rule #21; r2-verified)
  const int srow  = tid >> 2;
  const int sslot = (((tid & 3) ^ ((tid >> 3) & 3)) << 3);
  const u16* gA = A + (size_t)(bm + srow) * K + sslot;
  const u16* gB = B + (size_t)(bn + srow) * K + sslot;

  auto stageA = [&](int par, int ks, int kt) {
    u16* d = &lds[(par * 2 + ks) * 8192 + wid * 512];
    const u16* s = gA + kt * 64 + ks * 32;
#pragma unroll
    for (int i = 0; i < 2; ++i)
      __builtin_amdgcn_global_load_lds(
          (__attribute__((address_space(1))) const void*)(s + (size_t)i * 128 * K),
          (__attribute__((address_space(3))) void*)(d + i * 4096), 16, 0, 0);
  };
  auto stageB = [&](int par, int ks, int kt) {
    u16* d = &lds[32768 + (par * 2 + ks) * 8192 + wid * 512];
    const u16* s = gB + kt * 64 + ks * 32;
#pragma unroll
    for (int i = 0; i < 2; ++i)
      __builtin_amdgcn_global_load_lds(
          (__attribute__((address_space(1))) const void*)(s + (size_t)i * 128 * K),
          (__attribute__((address_space(3))) void*)(d + i * 4096), 16, 0, 0);
  };

  // LDS fragment readers (explicit parity)
  auto ldA = [&](int par, int ks, int mf) -> bf16x8 {
    return *(const bf16x8*)&lds[(par * 2 + ks) * 8192 + (wmL + mf * 16 + lr) * 32 + rslot];
  };
  auto ldB = [&](int par, int ks, int nf) -> bf16x8 {
    return *(const bf16x8*)&lds[32768 + (par * 2 + ks) * 8192 + (wnL + nf * 16 + lr) * 32 + rslot];
  };

  f32x4 acc[8][4];
#pragma unroll
  for (int i = 0; i < 8; ++i)
#pragma unroll
    for (int n = 0; n < 4; ++n) acc[i][n] = f32x4{0.f, 0.f, 0.f, 0.f};

  const int NT = K >> 6;
  // prologue: stage chunk 0 fully (A00,B00,A01,B01 = 8 DMA ops)
  stageA(0, 0, 0); stageB(0, 0, 0); stageA(0, 1, 0); stageB(0, 1, 0);
  asm volatile("s_waitcnt vmcnt(4)" ::: "memory");   // A00,B00 resident
  __builtin_amdgcn_s_barrier();

  bf16x8 aE[4], aO[4], b0[4], b1[4];
  // preload phase-0 fragments (par=0, kp0, m-half 0)
#pragma unroll
  for (int n = 0; n < 4; ++n) b0[n] = ldB(0, 0, n);
#pragma unroll
  for (int m = 0; m < 4; ++m) aE[m] = ldA(0, 0, m);

#define VM4() asm volatile("s_waitcnt vmcnt(4)" ::: "memory")
#define BAR() __builtin_amdgcn_s_barrier()

  for (int t = 0; t < NT; ++t) {
    const int par = t & 1, npar = par ^ 1;
    const int tn = (t + 1 < NT) ? t + 1 : 0;   // wrap keeps vmcnt count uniform

    // ---- phase 0: consume (aE, b0) = kp0 x m0-3 ; prefetch aO = kp0 m4-7 ----
    stageA(npar, 0, tn);
#pragma unroll
    for (int m = 0; m < 4; ++m) aO[m] = ldA(par, 0, 4 + m);
    __builtin_amdgcn_s_setprio(1);
#pragma unroll
    for (int m = 0; m < 4; ++m)
#pragma unroll
      for (int n = 0; n < 4; ++n)
        acc[m][n] = __builtin_amdgcn_mfma_f32_16x16x32_bf16(aE[m], b0[n], acc[m][n], 0, 0, 0);
    __builtin_amdgcn_s_setprio(0);

    // ---- phase 1: consume (aO, b0) = kp0 x m4-7 ; gate ; prefetch (b1, aE) = kp1 ----
    stageB(npar, 0, tn);
    VM4();   // retires A(par,1), B(par,1) -> kp1 slabs resident
    BAR();
#pragma unroll
    for (int n = 0; n < 4; ++n) b1[n] = ldB(par, 1, n);
#pragma unroll
    for (int m = 0; m < 4; ++m) aE[m] = ldA(par, 1, m);
    __builtin_amdgcn_s_setprio(1);
#pragma unroll
    for (int m = 0; m < 4; ++m)
#pragma unroll
      for (int n = 0; n < 4; ++n)
        acc[4 + m][n] = __builtin_amdgcn_mfma_f32_16x16x32_bf16(aO[m], b0[n], acc[4 + m][n], 0, 0, 0);
    __builtin_amdgcn_s_setprio(0);

    // ---- phase 2: consume (aE, b1) = kp1 x m0-3 ; prefetch aO = kp1 m4-7 ----
    stageA(npar, 1, tn);
#pragma unroll
    for (int m = 0; m < 4; ++m) aO[m] = ldA(par, 1, 4 + m);
    __builtin_amdgcn_s_setprio(1);
#pragma unroll
    for (int m = 0; m < 4; ++m)
#pragma unroll
      for (int n = 0; n < 4; ++n)
        acc[m][n] = __builtin_amdgcn_mfma_f32_16x16x32_bf16(aE[m], b1[n], acc[m][n], 0, 0, 0);
    __builtin_amdgcn_s_setprio(0);

    // ---- phase 3: consume (aO, b1) = kp1 x m4-7 ; gate ; prefetch (b0, aE) = next kp0 ----
    stageB(npar, 1, tn);
    VM4();   // retires A(npar,0), B(npar,0) -> next chunk's kp0 slabs resident
    BAR();
#pragma unroll
    for (int n = 0; n < 4; ++n) b0[n] = ldB(npar, 0, n);
#pragma unroll
    for (int m = 0; m < 4; ++m) aE[m] = ldA(npar, 0, m);
    __builtin_amdgcn_s_setprio(1);
#pragma unroll
    for (int m = 0; m < 4; ++m)
#pragma unroll
      for (int n = 0; n < 4; ++n)
        acc[4 + m][n] = __builtin_amdgcn_mfma_f32_16x16x32_bf16(aO[m], b1[n], acc[4 + m][n], 0, 0, 0);
    __builtin_amdgcn_s_setprio(0);
  }

  // drain wrapped staging DMAs before LDS dealloc / kernel end
  asm volatile("s_waitcnt vmcnt(0)" ::: "memory");
  __builtin_amdgcn_s_barrier();

  // epilogue: C/D layout col = lane&15, row = (lane>>4)*4 + j
#pragma unroll
  for (int nf = 0; nf < 4; ++nf) {
    const int col = bn + wnL + nf * 16 + lr;
    const float bv = bias[col];
#pragma unroll
    for (int mf = 0; mf < 8; ++mf) {
      const int row = bm + wmL + mf * 16 + lk * 4;
#pragma unroll
      for (int j = 0; j < 4; ++j)
        C[(size_t)(row + j) * N + col] = acc[mf][nf][j] + bv;
    }
  }
#undef VM4
#undef BAR
}

extern "C" void kernel_launch(void* const* d_in, const int* in_sizes, int n_in,
                              void* d_out, int out_size, void* d_ws, size_t ws_size,
                              hipStream_t stream) {
  const float* x  = (const float*)d_in[0];
  const float* w  = (const float*)d_in[1];
  const float* lA = (const float*)d_in[2];
  const float* lB = (const float*)d_in[3];
  const float* bs = (const float*)d_in[4];
  float* out = (float*)d_out;

  const int DOUT = in_sizes[4];              // 4096
  const int DIN  = in_sizes[1] / DOUT;       // 4096
  const int M    = in_sizes[0] / DIN;        // 8192

  u16* Xb = (u16*)d_ws;                      // M*DIN bf16
  u16* Wb = Xb + (size_t)M * DIN;            // DOUT*DIN bf16

  const int n4 = (M * DIN) / 4;
  const int nW   = DOUT / 4;                 // 1024 weff blocks (first)
  const int nCvt = 2048;                     // cvt blocks (backfill)
  aux_kernel<<<nW + nCvt, 256, 0, stream>>>((const float4*)x, (u16x4*)Xb, n4, nW, nCvt,
                                            w, lA, lB, Wb, DIN);

  (void)hipFuncSetAttribute((const void*)gemm256_kernel,
                            hipFuncAttributeMaxDynamicSharedMemorySize, 131072);

  const int nwg = (M / BM) * (DOUT / BN);    // 512
  gemm256_kernel<<<nwg, 512, 131072, stream>>>(Xb, Wb, bs, out, M, DOUT, DIN);
}